// Round 7
// baseline (459.443 us; speedup 1.0000x reference)
//
#include <hip/hip_runtime.h>
#include <math.h>

#define B_ 4
#define CIN_ 32
#define HID_ 32
#define T_ 31
#define H_ 96
#define W_ 96
#define SP_ (H_*W_)

typedef _Float16 half8 __attribute__((ext_vector_type(8)));
typedef float f32x4 __attribute__((ext_vector_type(4)));
typedef float f32x16 __attribute__((ext_vector_type(16)));

// ---------------------------------------------------------------------------
// Kernel 0: weights fp32 -> fp16 gate-interleaved MFMA A-fragments.
// wr[((ocg*27 + tap)*64 + lane)*8 + i]
//   m = lane&15: gate = m&1, ch = ocg*8 + (m>>1); global oc = gate*32 + ch
//   cin = (lane>>4)*8 + i
// ---------------------------------------------------------------------------
__global__ __launch_bounds__(256) void prep_w_kernel(
    const float* __restrict__ w, _Float16* __restrict__ wr) {
  int idx = blockIdx.x * 256 + threadIdx.x;
  if (idx >= 55296) return;
  int i = idx & 7;
  int lane = (idx >> 3) & 63;
  int rest = idx >> 9;             // ocg*27 + tap
  int tap = rest % 27;
  int ocg = rest / 27;
  int m = lane & 15;
  int cin = (lane >> 4) * 8 + i;
  int oc = (m & 1) * 32 + ocg * 8 + (m >> 1);
  wr[idx] = (_Float16)(w[(oc * CIN_ + cin) * 27 + tap]);
}

// ---------------------------------------------------------------------------
// Kernel 1: fused Conv3d (fp16 MFMA) + gating + time recurrence.
// Grid (192,4) = 768 blocks = exactly 3/CU (even). Tile 16x3 px.
// Block 256 thr = 4 waves (wave = ocg: 8 ch x {Z,F} gate-interleaved).
// Weights 27 half8 = 108 VGPR/wave, held whole kernel.
// Ring: 4 slots x [5 rows x 18 cols][pitch 40] = 28.8 KB LDS -> 3 blocks/CU,
// 3 waves/SIMD. Stage loads (10 interior + 2 edge) at top of t, ds_writes
// after compute, one barrier/t.
// ---------------------------------------------------------------------------
#define PITCH 40
#define SROWS 5
#define SCOLS 18
#define SLICE_HF (SROWS * SCOLS * PITCH)   // 3600 f16 = 7200 B

__global__ __launch_bounds__(256, 3) void conv_rec_mfma(
    const float* __restrict__ in, const _Float16* __restrict__ wr,
    const float* __restrict__ bias, float* __restrict__ out) {
  __shared__ _Float16 in_s[4 * SLICE_HF];   // 28800 B

  const int tid = threadIdx.x;
  const int tile = blockIdx.x;   // 0..191
  const int b = blockIdx.y;      // 0..3
  const int x0 = (tile % 6) * 16;
  const int y0 = (tile / 6) * 3;
  const int lane = tid & 63;
  const int ocg = tid >> 6;      // 0..3
  const int px = lane & 15;
  const int kq = lane >> 4;      // 0..3

  // --- per-wave weights: 27 taps, gate-interleaved 16-slot frags ---
  half8 wreg[27];
  {
    const _Float16* wp = wr + (size_t)ocg * 27 * 512 + lane * 8;
#pragma unroll
    for (int tap = 0; tap < 27; ++tap)
      wreg[tap] = *(const half8*)(wp + tap * 512);
  }

  const int c0 = ocg * 8 + 2 * kq;
  f32x4 bias4;
  bias4[0] = bias[c0];
  bias4[1] = bias[32 + c0];
  bias4[2] = bias[c0 + 1];
  bias4[3] = bias[32 + c0 + 1];

  // staging roles: interior = 16 groups x 16 px; 160 rowjobs (yy*32+cin)
  const int s_xi = tid & 15;
  const int s_q  = tid >> 4;       // 0..15, handles rowjobs s_q + 16k, k<10
  const int e_cin = tid & 31;      // edge role (tid < 160)
  const int e_yy  = tid >> 5;
  const int e_gy  = y0 - 1 + e_yy;
  const bool e_act = (tid < 160) && ((unsigned)e_gy < (unsigned)H_);

  auto stage_full = [&](int ts) {
    _Float16* dst = in_s + (ts & 3) * SLICE_HF;
    const float* sb = in + ((size_t)(b * CIN_) * T_ + ts) * SP_;
#pragma unroll
    for (int k = 0; k < 10; ++k) {
      int rj = k * 16 + s_q;          // yy*32 + cin
      int cin = rj & 31;
      int yy = rj >> 5;
      int gy = y0 - 1 + yy;
      float v = 0.f;
      if ((unsigned)gy < (unsigned)H_)
        v = sb[(size_t)cin * (T_ * SP_) + gy * W_ + x0 + s_xi];
      dst[(yy * SCOLS + s_xi + 1) * PITCH + cin] = (_Float16)v;
    }
    float v0 = 0.f, v1 = 0.f;
    if (e_act) {
      const float* rb = sb + (size_t)e_cin * (T_ * SP_) + e_gy * W_;
      if (x0 > 0) v0 = rb[x0 - 1];
      if (x0 + 16 < W_) v1 = rb[x0 + 16];
    }
    if (tid < 160) {
      dst[(e_yy * SCOLS + 0) * PITCH + e_cin] = (_Float16)v0;
      dst[(e_yy * SCOLS + 17) * PITCH + e_cin] = (_Float16)v1;
    }
  };

  // prologue: slot 3 = slice -1 = zeros; slices 0,1 -> slots 0,1
  {
    uint32_t* dz = (uint32_t*)(in_s + 3 * SLICE_HF);
    for (int e = tid; e < SLICE_HF / 2; e += 256) dz[e] = 0u;
  }
  stage_full(0);
  stage_full(1);
  __syncthreads();

  float h[3][2];
#pragma unroll
  for (int r = 0; r < 3; ++r) { h[r][0] = 0.f; h[r][1] = 0.f; }

  size_t obase = ((size_t)(b * HID_ + c0) * T_) * SP_ + y0 * W_ + x0 + px;

  for (int t = 0; t < T_; ++t) {
    const int ts = t + 2;

    // ---- phase A: issue stage loads for slice ts (held in regs) ----
    float sv[10], ev0 = 0.f, ev1 = 0.f;
    if (ts < T_) {
      const float* sb = in + ((size_t)(b * CIN_) * T_ + ts) * SP_;
#pragma unroll
      for (int k = 0; k < 10; ++k) {
        int rj = k * 16 + s_q;
        int cin = rj & 31;
        int yy = rj >> 5;
        int gy = y0 - 1 + yy;
        sv[k] = 0.f;
        if ((unsigned)gy < (unsigned)H_)
          sv[k] = sb[(size_t)cin * (T_ * SP_) + gy * W_ + x0 + s_xi];
      }
      if (e_act) {
        const float* rb = sb + (size_t)e_cin * (T_ * SP_) + e_gy * W_;
        if (x0 > 0) ev0 = rb[x0 - 1];
        if (x0 + 16 < W_) ev1 = rb[x0 + 16];
      }
    }

    // ---- compute: 27 taps x 3 rows ----
    f32x4 acc[3];
#pragma unroll
    for (int r = 0; r < 3; ++r) acc[r] = bias4;

#pragma unroll
    for (int kd = 0; kd < 3; ++kd) {
      const _Float16* sb2 = in_s + ((t + 3 + kd) & 3) * SLICE_HF;  // slice t-1+kd
#pragma unroll
      for (int kw = 0; kw < 3; ++kw) {
        half8 brow[5];
#pragma unroll
        for (int rr = 0; rr < 5; ++rr)
          brow[rr] = *(const half8*)(sb2 + (rr * SCOLS + px + kw) * PITCH + kq * 8);
#pragma unroll
        for (int kh = 0; kh < 3; ++kh) {
          const int tap = kd * 9 + kh * 3 + kw;
#pragma unroll
          for (int r = 0; r < 3; ++r)
            acc[r] = __builtin_amdgcn_mfma_f32_16x16x32_f16(wreg[tap], brow[r + kh], acc[r], 0, 0, 0);
        }
      }
    }

    // ---- phase B: write staged slice (or zeros for ts==31) ----
    if (ts < T_) {
      _Float16* dst = in_s + (ts & 3) * SLICE_HF;
#pragma unroll
      for (int k = 0; k < 10; ++k) {
        int rj = k * 16 + s_q;
        int cin = rj & 31;
        int yy = rj >> 5;
        dst[(yy * SCOLS + s_xi + 1) * PITCH + cin] = (_Float16)sv[k];
      }
      if (tid < 160) {
        dst[(e_yy * SCOLS + 0) * PITCH + e_cin] = (_Float16)ev0;
        dst[(e_yy * SCOLS + 17) * PITCH + e_cin] = (_Float16)ev1;
      }
    } else if (ts == T_) {
      uint32_t* dz = (uint32_t*)(in_s + (ts & 3) * SLICE_HF);
      for (int e = tid; e < SLICE_HF / 2; e += 256) dz[e] = 0u;
    }

    // ---- gating + recurrence + store ----
#pragma unroll
    for (int r = 0; r < 3; ++r) {
      float z0 = 1.f - 2.f / (1.f + __expf(2.f * acc[r][0]));
      float f0 = 1.f / (1.f + __expf(-acc[r][1]));
      h[r][0] = f0 * h[r][0] + (1.f - f0) * z0;
      out[obase + r * W_] = h[r][0];
      float z1 = 1.f - 2.f / (1.f + __expf(2.f * acc[r][2]));
      float f1 = 1.f / (1.f + __expf(-acc[r][3]));
      h[r][1] = f1 * h[r][1] + (1.f - f1) * z1;
      out[obase + (size_t)T_ * SP_ + r * W_] = h[r][1];
    }
    obase += SP_;
    __syncthreads();   // stage writes visible; ring slot safety
  }
}

// ---------------------------------------------------------------------------
// Kernel 2: per-pixel channel attention via 32x32x16 MFMA, in-place on d_out.
// PX=16/block, 512 thr. Plane stride 1288 halfs (644 dw = 4 mod 32 banks ->
// transpose staging is 2-way, free). float4 staging (4 px/thread).
// ---------------------------------------------------------------------------
#define APIT 40
#define PSTR 1288   // padded per-pixel plane stride (halfs)

__global__ __launch_bounds__(512) void attn_mfma(
    float* __restrict__ out, const float* __restrict__ gamma) {
  __shared__ _Float16 qh_s[16 * PSTR];      // 41216 B
  __shared__ _Float16 qt_s[16 * PSTR];      // 41216 B
  __shared__ _Float16 at_s[8 * 32 * APIT];  // 20480 B

  const int tid = threadIdx.x;
  const int x0 = blockIdx.x * 16;
  const int y = blockIdx.y;
  const int b = blockIdx.z;
  const int lane = tid & 63;
  const int wv = tid >> 6;       // 0..7
  const float gm = gamma[0];

  // stage h: float4 reads (4 px), transpose-scatter to both layouts
  for (int e = tid; e < 4 * 992; e += 512) {
    int xi4 = e & 3;
    int q = e >> 2;              // 0..991
    int t = q % 31;
    int c = q / 31;
    float4 v = *(const float4*)&out[((size_t)(b * HID_ + c) * T_ + t) * SP_ +
                                    y * W_ + x0 + xi4 * 4];
#pragma unroll
    for (int j = 0; j < 4; ++j) {
      int xi = xi4 * 4 + j;
      _Float16 hv = (_Float16)(&v.x)[j];
      qh_s[xi * PSTR + c * APIT + t] = hv;
      qt_s[xi * PSTR + t * APIT + c] = hv;
    }
  }
  // zero-pad t=31 of qh (16 px x 32 c = 512 elems)
  qh_s[(tid & 15) * PSTR + (tid >> 4) * APIT + 31] = (_Float16)0.f;
  __syncthreads();

  const int cd = lane & 31;
  const int hi = lane >> 5;

#pragma unroll
  for (int pp = 0; pp < 2; ++pp) {
    const int px = wv * 2 + pp;
    const _Float16* qs = qh_s + px * PSTR;
    const _Float16* qt = qt_s + px * PSTR;
    _Float16* as = at_s + wv * (32 * APIT);

    // QK^T: S[c][d] = sum_t qh[c][t] qh[d][t]
    half8 q0 = *(const half8*)(qs + cd * APIT + hi * 8);
    half8 q1 = *(const half8*)(qs + cd * APIT + hi * 8 + 16);
    f32x16 S = {};
    S = __builtin_amdgcn_mfma_f32_32x32x16_f16(q0, q0, S, 0, 0, 0);
    S = __builtin_amdgcn_mfma_f32_32x32x16_f16(q1, q1, S, 0, 0, 0);

    // softmax over c (rows in regs + lane^32), then * 1/sqrt(32)
    float mx = S[0];
#pragma unroll
    for (int r = 1; r < 16; ++r) mx = fmaxf(mx, S[r]);
    mx = fmaxf(mx, __shfl_xor(mx, 32));
    float sm = 0.f;
    float ev[16];
#pragma unroll
    for (int r = 0; r < 16; ++r) { ev[r] = __expf(S[r] - mx); sm += ev[r]; }
    sm += __shfl_xor(sm, 32);
    const float sc = 0.17677669529663688f / sm;

#pragma unroll
    for (int r = 0; r < 16; ++r) {
      int c = (r & 3) + 8 * (r >> 2) + 4 * hi;
      as[c * APIT + cd] = (_Float16)(ev[r] * sc);
    }

    // PV: P[c][t] = sum_d attn[c][d] qh[d][t]
    half8 a0 = *(const half8*)(as + cd * APIT + hi * 8);
    half8 a1 = *(const half8*)(as + cd * APIT + hi * 8 + 16);
    half8 b0 = *(const half8*)(qt + cd * APIT + hi * 8);
    half8 b1 = *(const half8*)(qt + cd * APIT + hi * 8 + 16);
    f32x16 P = {};
    P = __builtin_amdgcn_mfma_f32_32x32x16_f16(a0, b0, P, 0, 0, 0);
    P = __builtin_amdgcn_mfma_f32_32x32x16_f16(a1, b1, P, 0, 0, 0);

    // result (lane holds t = cd, c in regs) -> qt[t*APIT + c]
#pragma unroll
    for (int r = 0; r < 16; ++r) {
      int c = (r & 3) + 8 * (r >> 2) + 4 * hi;
      qt_s[px * PSTR + cd * APIT + c] = (_Float16)P[r];
    }
  }
  __syncthreads();

  // store: out = gamma * ah + h (float4 writes)
  for (int e = tid; e < 4 * 992; e += 512) {
    int xi4 = e & 3;
    int q = e >> 2;
    int t = q % 31;
    int c = q / 31;
    float4 rv;
#pragma unroll
    for (int j = 0; j < 4; ++j) {
      int xi = xi4 * 4 + j;
      float ah = (float)qt_s[xi * PSTR + t * APIT + c];
      float hv = (float)qh_s[xi * PSTR + c * APIT + t];
      (&rv.x)[j] = gm * ah + hv;
    }
    *(float4*)&out[((size_t)(b * HID_ + c) * T_ + t) * SP_ + y * W_ + x0 +
                   xi4 * 4] = rv;
  }
}

// ---------------------------------------------------------------------------
extern "C" void kernel_launch(void* const* d_in, const int* in_sizes, int n_in,
                              void* d_out, int out_size, void* d_ws,
                              size_t ws_size, hipStream_t stream) {
  const float* in    = (const float*)d_in[0];  // [4,32,31,96,96]
  const float* w     = (const float*)d_in[1];  // [64,32,3,3,3]
  const float* bias  = (const float*)d_in[2];  // [64]
  const float* gamma = (const float*)d_in[3];  // [1]
  float* out = (float*)d_out;                  // [4,32,31,96,96]
  _Float16* wr = (_Float16*)d_ws;              // 110 KB fp16 fragments

  prep_w_kernel<<<216, 256, 0, stream>>>(w, wr);
  conv_rec_mfma<<<dim3(192, 4), 256, 0, stream>>>(in, wr, bias, out);
  attn_mfma<<<dim3(6, 96, 4), 512, 0, stream>>>(out, gamma);
}

// Round 8
// 423.707 us; speedup vs baseline: 1.0843x; 1.0843x over previous
//
#include <hip/hip_runtime.h>
#include <math.h>

#define B_ 4
#define CIN_ 32
#define HID_ 32
#define T_ 31
#define H_ 96
#define W_ 96
#define SP_ (H_*W_)
#define TC_ 4          // t-steps per conv block
#define NCH_ 8         // t-chunks (last covers 3)

typedef _Float16 half8 __attribute__((ext_vector_type(8)));
typedef float f32x4 __attribute__((ext_vector_type(4)));
typedef float f32x16 __attribute__((ext_vector_type(16)));

static __device__ inline unsigned int packzf(float z, float f) {
  unsigned short uz = __builtin_bit_cast(unsigned short, (_Float16)z);
  unsigned short uf = __builtin_bit_cast(unsigned short, (_Float16)f);
  return (unsigned int)uz | ((unsigned int)uf << 16);
}

// ---------------------------------------------------------------------------
// Kernel 0: weights fp32 -> fp16 gate-interleaved MFMA A-fragments.
// wr[((ocg*27 + tap)*64 + lane)*8 + i]
//   m = lane&15: gate = m&1, ch = ocg*8 + (m>>1); oc = gate*32 + ch
//   cin = (lane>>4)*8 + i
// ---------------------------------------------------------------------------
__global__ __launch_bounds__(256) void prep_w_kernel(
    const float* __restrict__ w, _Float16* __restrict__ wr) {
  int idx = blockIdx.x * 256 + threadIdx.x;
  if (idx >= 55296) return;
  int i = idx & 7;
  int lane = (idx >> 3) & 63;
  int rest = idx >> 9;             // ocg*27 + tap
  int tap = rest % 27;
  int ocg = rest / 27;
  int m = lane & 15;
  int cin = (lane >> 4) * 8 + i;
  int oc = (m & 1) * 32 + ocg * 8 + (m >> 1);
  wr[idx] = (_Float16)(w[(oc * CIN_ + cin) * 27 + tap]);
}

// ---------------------------------------------------------------------------
// Kernel 1: t-PARALLEL Conv3d (fp16 MFMA) + activations; NO recurrence.
// Grid (96 tiles, 8 t-chunks, 4 batch) = 3072 blocks = 12/CU.
// Block 256 thr = 4 waves (wave = ocg: 8 ch x {Z,F} gate-interleaved),
// tile 16x6, weights 27 half8 = 108 VGPR/wave held whole kernel.
// LDS: 6 slots x [8 rows x 18 cols][pitch 40] = 69 KB -> 2 blocks/CU.
// Slot s holds slice tc0-1+s (no ring reuse -> single barrier/t for
// visibility only). Iter k stages slice tc0+k+2 (k<3).
// Output: (tanh z, sigm f) packed fp16x2 -> d_out as u32 [b][32][t][sp].
// ---------------------------------------------------------------------------
#define PITCH 40
#define SROWS 8
#define SCOLS 18
#define SLICE_HF (SROWS * SCOLS * PITCH)   // 5760 f16 = 11520 B

__global__ __launch_bounds__(256, 2) void conv_gates_mfma(
    const float* __restrict__ in, const _Float16* __restrict__ wr,
    const float* __restrict__ bias, unsigned int* __restrict__ gout) {
  __shared__ _Float16 in_s[6 * SLICE_HF];   // 69120 B

  const int tid = threadIdx.x;
  const int tile = blockIdx.x;   // 0..95
  const int tc0 = blockIdx.y * TC_;
  const int b = blockIdx.z;
  const int x0 = (tile % 6) * 16;
  const int y0 = (tile / 6) * 6;
  const int lane = tid & 63;
  const int ocg = tid >> 6;
  const int px = lane & 15;
  const int kq = lane >> 4;

  // per-wave weights: 27 taps, gate-interleaved 16-slot frags
  half8 wreg[27];
  {
    const _Float16* wp = wr + (size_t)ocg * 27 * 512 + lane * 8;
#pragma unroll
    for (int tap = 0; tap < 27; ++tap)
      wreg[tap] = *(const half8*)(wp + tap * 512);
  }

  const int c0 = ocg * 8 + 2 * kq;
  f32x4 bias4;
  bias4[0] = bias[c0];
  bias4[1] = bias[32 + c0];
  bias4[2] = bias[c0 + 1];
  bias4[3] = bias[32 + c0 + 1];

  // staging roles (R6 pattern): interior 16 jobs x 16 px; edges 8 rows x 32 cin
  const int s_xi = tid & 15;
  const int s_q  = tid >> 4;        // 0..15
  const int e_cin = tid & 31;
  const int e_yy  = tid >> 5;       // 0..7
  const int e_gy  = y0 - 1 + e_yy;
  const bool e_ok = ((unsigned)e_gy < (unsigned)H_);

  auto zero_slot = [&](int slot) {
    uint32_t* dz = (uint32_t*)(in_s + slot * SLICE_HF);
    for (int e = tid; e < SLICE_HF / 2; e += 256) dz[e] = 0u;
  };
  auto stage_full = [&](int ts, int slot) {
    _Float16* dst = in_s + slot * SLICE_HF;
    const float* sb = in + ((size_t)(b * CIN_) * T_ + ts) * SP_;
#pragma unroll
    for (int k = 0; k < 16; ++k) {
      int rj = k * 16 + s_q;          // yy*32 + cin
      int cin = rj & 31;
      int yy = rj >> 5;
      int gy = y0 - 1 + yy;
      float v = 0.f;
      if ((unsigned)gy < (unsigned)H_)
        v = sb[(size_t)cin * (T_ * SP_) + gy * W_ + x0 + s_xi];
      dst[(yy * SCOLS + s_xi + 1) * PITCH + cin] = (_Float16)v;
    }
    float v0 = 0.f, v1 = 0.f;
    if (e_ok) {
      const float* rb = sb + (size_t)e_cin * (T_ * SP_) + e_gy * W_;
      if (x0 > 0) v0 = rb[x0 - 1];
      if (x0 + 16 < W_) v1 = rb[x0 + 16];
    }
    dst[(e_yy * SCOLS + 0) * PITCH + e_cin] = (_Float16)v0;
    dst[(e_yy * SCOLS + 17) * PITCH + e_cin] = (_Float16)v1;
  };

  // prologue: slots 0,1,2 = slices tc0-1, tc0, tc0+1
  if (tc0 == 0) zero_slot(0); else stage_full(tc0 - 1, 0);
  stage_full(tc0, 1);
  stage_full(tc0 + 1, 2);
  __syncthreads();

  for (int k = 0; k < TC_; ++k) {
    const int t = tc0 + k;
    if (t >= T_) break;             // uniform across block

    // ---- phase A: issue stage loads for slice ts = t+2 (held in regs) ----
    const int ts = t + 2;
    const bool do_stage = (k < 3);
    float sv[16], ev0 = 0.f, ev1 = 0.f;
    if (do_stage && ts < T_) {
      const float* sb = in + ((size_t)(b * CIN_) * T_ + ts) * SP_;
#pragma unroll
      for (int kk = 0; kk < 16; ++kk) {
        int rj = kk * 16 + s_q;
        int cin = rj & 31;
        int yy = rj >> 5;
        int gy = y0 - 1 + yy;
        sv[kk] = 0.f;
        if ((unsigned)gy < (unsigned)H_)
          sv[kk] = sb[(size_t)cin * (T_ * SP_) + gy * W_ + x0 + s_xi];
      }
      if (e_ok) {
        const float* rb = sb + (size_t)e_cin * (T_ * SP_) + e_gy * W_;
        if (x0 > 0) ev0 = rb[x0 - 1];
        if (x0 + 16 < W_) ev1 = rb[x0 + 16];
      }
    }

    // ---- compute: 27 taps x 6 rows; slices at slots k..k+2 ----
    f32x4 acc[6];
#pragma unroll
    for (int r = 0; r < 6; ++r) acc[r] = bias4;

#pragma unroll
    for (int kd = 0; kd < 3; ++kd) {
      const _Float16* sb2 = in_s + (k + kd) * SLICE_HF;   // slice t-1+kd
#pragma unroll
      for (int kw = 0; kw < 3; ++kw) {
        half8 brow[8];
#pragma unroll
        for (int rr = 0; rr < 8; ++rr)
          brow[rr] = *(const half8*)(sb2 + (rr * SCOLS + px + kw) * PITCH + kq * 8);
#pragma unroll
        for (int kh = 0; kh < 3; ++kh) {
          const int tap = kd * 9 + kh * 3 + kw;
#pragma unroll
          for (int r = 0; r < 6; ++r)
            acc[r] = __builtin_amdgcn_mfma_f32_16x16x32_f16(wreg[tap], brow[r + kh], acc[r], 0, 0, 0);
        }
      }
    }

    // ---- phase B: write staged slice to slot k+3 ----
    if (do_stage) {
      if (ts < T_) {
        _Float16* dst = in_s + (k + 3) * SLICE_HF;
#pragma unroll
        for (int kk = 0; kk < 16; ++kk) {
          int rj = kk * 16 + s_q;
          int cin = rj & 31;
          int yy = rj >> 5;
          dst[(yy * SCOLS + s_xi + 1) * PITCH + cin] = (_Float16)sv[kk];
        }
        dst[(e_yy * SCOLS + 0) * PITCH + e_cin] = (_Float16)ev0;
        dst[(e_yy * SCOLS + 17) * PITCH + e_cin] = (_Float16)ev1;
      } else if (ts == T_) {
        zero_slot(k + 3);           // slice 31 = zeros (only chunk 7 hits)
      }
    }

    // ---- activations + pack + store (z,f) for c0, c0+1 ----
    size_t ob = ((size_t)(b * HID_ + c0) * T_ + t) * SP_ + y0 * W_ + x0 + px;
#pragma unroll
    for (int r = 0; r < 6; ++r) {
      float z0 = 1.f - 2.f / (1.f + __expf(2.f * acc[r][0]));
      float f0 = 1.f / (1.f + __expf(-acc[r][1]));
      gout[ob + r * W_] = packzf(z0, f0);
      float z1 = 1.f - 2.f / (1.f + __expf(2.f * acc[r][2]));
      float f1 = 1.f / (1.f + __expf(-acc[r][3]));
      gout[ob + (size_t)T_ * SP_ + r * W_] = packzf(z1, f1);
    }
    __syncthreads();   // slot k+3 visible before iter k+1 reads it
  }
}

// ---------------------------------------------------------------------------
// Kernel 1b: gated time recurrence, IN-PLACE on d_out.
// Thread owns (b, c, 4 px): reads uint4 (4x packed z,f) at t, writes float4 h
// to the SAME slot (read-before-write per thread = safe). Coalesced 16B/lane.
// ---------------------------------------------------------------------------
__global__ __launch_bounds__(256) void rec_kernel(unsigned int* __restrict__ g) {
  int v = blockIdx.x * 256 + threadIdx.x;    // 0..294911
  int sp4 = v % (SP_ / 4);
  int bc = v / (SP_ / 4);                    // b*32 + c
  unsigned int* base = g + (size_t)bc * T_ * SP_ + sp4 * 4;
  f32x4 h = {0.f, 0.f, 0.f, 0.f};
  for (int t = 0; t < T_; ++t) {
    uint4 gv = *(uint4*)(base + (size_t)t * SP_);
#pragma unroll
    for (int j = 0; j < 4; ++j) {
      unsigned int gw = (&gv.x)[j];
      float z = (float)__builtin_bit_cast(_Float16, (unsigned short)(gw & 0xffff));
      float f = (float)__builtin_bit_cast(_Float16, (unsigned short)(gw >> 16));
      h[j] = f * (h[j] - z) + z;             // f*h + (1-f)*z
    }
    *(f32x4*)(base + (size_t)t * SP_) = h;
  }
}

// ---------------------------------------------------------------------------
// Kernel 2: per-pixel channel attention via 32x32x16 MFMA, in-place on d_out.
// (R7 version — prediction matched)
// ---------------------------------------------------------------------------
#define APIT 40
#define PSTR 1288

__global__ __launch_bounds__(512) void attn_mfma(
    float* __restrict__ out, const float* __restrict__ gamma) {
  __shared__ _Float16 qh_s[16 * PSTR];
  __shared__ _Float16 qt_s[16 * PSTR];
  __shared__ _Float16 at_s[8 * 32 * APIT];

  const int tid = threadIdx.x;
  const int x0 = blockIdx.x * 16;
  const int y = blockIdx.y;
  const int b = blockIdx.z;
  const int lane = tid & 63;
  const int wv = tid >> 6;
  const float gm = gamma[0];

  for (int e = tid; e < 4 * 992; e += 512) {
    int xi4 = e & 3;
    int q = e >> 2;
    int t = q % 31;
    int c = q / 31;
    float4 v = *(const float4*)&out[((size_t)(b * HID_ + c) * T_ + t) * SP_ +
                                    y * W_ + x0 + xi4 * 4];
#pragma unroll
    for (int j = 0; j < 4; ++j) {
      int xi = xi4 * 4 + j;
      _Float16 hv = (_Float16)(&v.x)[j];
      qh_s[xi * PSTR + c * APIT + t] = hv;
      qt_s[xi * PSTR + t * APIT + c] = hv;
    }
  }
  qh_s[(tid & 15) * PSTR + (tid >> 4) * APIT + 31] = (_Float16)0.f;
  __syncthreads();

  const int cd = lane & 31;
  const int hi = lane >> 5;

#pragma unroll
  for (int pp = 0; pp < 2; ++pp) {
    const int px = wv * 2 + pp;
    const _Float16* qs = qh_s + px * PSTR;
    const _Float16* qt = qt_s + px * PSTR;
    _Float16* as = at_s + wv * (32 * APIT);

    half8 q0 = *(const half8*)(qs + cd * APIT + hi * 8);
    half8 q1 = *(const half8*)(qs + cd * APIT + hi * 8 + 16);
    f32x16 S = {};
    S = __builtin_amdgcn_mfma_f32_32x32x16_f16(q0, q0, S, 0, 0, 0);
    S = __builtin_amdgcn_mfma_f32_32x32x16_f16(q1, q1, S, 0, 0, 0);

    float mx = S[0];
#pragma unroll
    for (int r = 1; r < 16; ++r) mx = fmaxf(mx, S[r]);
    mx = fmaxf(mx, __shfl_xor(mx, 32));
    float sm = 0.f;
    float ev[16];
#pragma unroll
    for (int r = 0; r < 16; ++r) { ev[r] = __expf(S[r] - mx); sm += ev[r]; }
    sm += __shfl_xor(sm, 32);
    const float sc = 0.17677669529663688f / sm;

#pragma unroll
    for (int r = 0; r < 16; ++r) {
      int c = (r & 3) + 8 * (r >> 2) + 4 * hi;
      as[c * APIT + cd] = (_Float16)(ev[r] * sc);
    }

    half8 a0 = *(const half8*)(as + cd * APIT + hi * 8);
    half8 a1 = *(const half8*)(as + cd * APIT + hi * 8 + 16);
    half8 b0 = *(const half8*)(qt + cd * APIT + hi * 8);
    half8 b1 = *(const half8*)(qt + cd * APIT + hi * 8 + 16);
    f32x16 P = {};
    P = __builtin_amdgcn_mfma_f32_32x32x16_f16(a0, b0, P, 0, 0, 0);
    P = __builtin_amdgcn_mfma_f32_32x32x16_f16(a1, b1, P, 0, 0, 0);

#pragma unroll
    for (int r = 0; r < 16; ++r) {
      int c = (r & 3) + 8 * (r >> 2) + 4 * hi;
      qt_s[px * PSTR + cd * APIT + c] = (_Float16)P[r];
    }
  }
  __syncthreads();

  for (int e = tid; e < 4 * 992; e += 512) {
    int xi4 = e & 3;
    int q = e >> 2;
    int t = q % 31;
    int c = q / 31;
    float4 rv;
#pragma unroll
    for (int j = 0; j < 4; ++j) {
      int xi = xi4 * 4 + j;
      float ah = (float)qt_s[xi * PSTR + t * APIT + c];
      float hv = (float)qh_s[xi * PSTR + c * APIT + t];
      (&rv.x)[j] = gm * ah + hv;
    }
    *(float4*)&out[((size_t)(b * HID_ + c) * T_ + t) * SP_ + y * W_ + x0 +
                   xi4 * 4] = rv;
  }
}

// ---------------------------------------------------------------------------
extern "C" void kernel_launch(void* const* d_in, const int* in_sizes, int n_in,
                              void* d_out, int out_size, void* d_ws,
                              size_t ws_size, hipStream_t stream) {
  const float* in    = (const float*)d_in[0];  // [4,32,31,96,96]
  const float* w     = (const float*)d_in[1];  // [64,32,3,3,3]
  const float* bias  = (const float*)d_in[2];  // [64]
  const float* gamma = (const float*)d_in[3];  // [1]
  float* out = (float*)d_out;                  // [4,32,31,96,96]
  _Float16* wr = (_Float16*)d_ws;              // 110 KB fp16 fragments

  prep_w_kernel<<<216, 256, 0, stream>>>(w, wr);
  conv_gates_mfma<<<dim3(96, NCH_, 4), 256, 0, stream>>>(
      in, wr, bias, (unsigned int*)d_out);
  rec_kernel<<<(B_ * HID_ * SP_ / 4 + 255) / 256, 256, 0, stream>>>(
      (unsigned int*)d_out);
  attn_mfma<<<dim3(6, 96, 4), 512, 0, stream>>>(out, gamma);
}